// Round 3
// baseline (750.303 us; speedup 1.0000x reference)
//
#include <hip/hip_runtime.h>

#define NLOC 12
#define F_DIM 512
#define H_DIM 256

typedef float f4 __attribute__((ext_vector_type(4)));
typedef _Float16 half4 __attribute__((ext_vector_type(4)));
typedef _Float16 half8 __attribute__((ext_vector_type(8)));

// workspace layout (bytes)
#define OFF_W1   0ul
#define OFF_W2   (OFF_W1 + 512ul*512*2)          // W1: [512][512] f16  (Bt: [n][k])
#define OFF_C1   (OFF_W2 + 512ul*1024*2)         // W2: [512][1024] f16 (Bt: [n][k])
#define OFF_CVEC (OFF_C1 + 2048ul)               // c1: [512] f32
// cvec: [512] f32

// ---------------------------------------------------------------------------
// mode 0: W1[f,j] = sum_h Wk[f,h] Wq[j,h]
// mode 1: W2[f,j]     = sum_h Wf[h,f]     Wv[j,h]
// mode 2: W2[f,512+j] = S * sum_h Wf[256+h,f] Wv[j,h]
// mode 3: c1[f] = sum_h bq[h] Wk[f,h] ;
//         cvec[f] = bv@Wf_top[:,f] + S*(bv@Wf_bot[:,f]) + b_dr*colsum(Wf_bot)[f] + bf[f]
// ---------------------------------------------------------------------------
__global__ void __launch_bounds__(256) precompute_w(
    const float* __restrict__ Wq, const float* __restrict__ Wk,
    const float* __restrict__ Wv, const float* __restrict__ Wf,
    const float* __restrict__ bq, const float* __restrict__ bv,
    const float* __restrict__ wdr, const float* __restrict__ bdr,
    const float* __restrict__ bfv,
    _Float16* __restrict__ W1, _Float16* __restrict__ W2,
    float* __restrict__ c1, float* __restrict__ cvec)
{
    const int mode = blockIdx.z;
    const int t = threadIdx.x;

    if (mode == 3) {
        if (blockIdx.y != 0 || blockIdx.x >= 2) return;
        const int f = blockIdx.x * 256 + t;   // 0..511
        f4 a = {0.f, 0.f, 0.f, 0.f};
        const f4* wk4 = (const f4*)(Wk + (long)f * H_DIM);
        const f4* bq4 = (const f4*)bq;
#pragma unroll 4
        for (int h4 = 0; h4 < H_DIM / 4; ++h4) a += wk4[h4] * bq4[h4];
        c1[f] = a[0] + a[1] + a[2] + a[3];

        float s1 = 0.f, s2 = 0.f, s3 = 0.f;
#pragma unroll 4
        for (int h = 0; h < H_DIM; ++h) {
            float w1v = Wf[h * F_DIM + f];
            float w2v = Wf[(H_DIM + h) * F_DIM + f];
            float bvh = bv[h];
            s1 += bvh * w1v; s2 += bvh * w2v; s3 += w2v;
        }
        float S = 0.f;
#pragma unroll
        for (int k = 0; k < NLOC; ++k) S += wdr[k];
        cvec[f] = s1 + S * s2 + bdr[0] * s3 + bfv[f];
        return;
    }

    __shared__ float X[32][264];
    __shared__ float Y[32][264];
    const int f0 = blockIdx.x * 32;
    const int j0 = blockIdx.y * 32;

    {
        const int r = t >> 3, cb = (t & 7) * 32;
        const float* ysrc = ((mode == 0) ? Wq : Wv) + (j0 + r) * H_DIM + cb;
#pragma unroll
        for (int u = 0; u < 32; u += 4)
            *(f4*)&Y[r][cb + u] = *(const f4*)(ysrc + u);
        if (mode == 0) {
            const float* xsrc = Wk + (f0 + r) * H_DIM + cb;
#pragma unroll
            for (int u = 0; u < 32; u += 4)
                *(f4*)&X[r][cb + u] = *(const f4*)(xsrc + u);
        }
    }
    if (mode != 0) {
        const int h = t;                       // 0..255
        const int hoff = (mode == 2) ? H_DIM : 0;
        const float* xsrc = Wf + (long)(h + hoff) * F_DIM + f0;
        f4 v[8];
#pragma unroll
        for (int u = 0; u < 8; ++u) v[u] = *(const f4*)(xsrc + u * 4);
#pragma unroll
        for (int r = 0; r < 32; ++r) X[r][h] = v[r >> 2][r & 3];
    }
    __syncthreads();

    const int fy = t >> 4, jx = t & 15;
    float a00 = 0.f, a01 = 0.f, a10 = 0.f, a11 = 0.f;
#pragma unroll 8
    for (int h = 0; h < H_DIM; ++h) {
        float x0 = X[fy][h], x1 = X[fy + 16][h];
        float y0 = Y[jx][h], y1 = Y[jx + 16][h];
        a00 += x0 * y0; a01 += x0 * y1; a10 += x1 * y0; a11 += x1 * y1;
    }
    if (mode == 2) {
        float S = 0.f;
#pragma unroll
        for (int k = 0; k < NLOC; ++k) S += wdr[k];
        a00 *= S; a01 *= S; a10 *= S; a11 *= S;
    }
    if (mode == 0) {
        W1[(f0 + fy) * F_DIM + (j0 + jx)]             = (_Float16)a00;
        W1[(f0 + fy) * F_DIM + (j0 + jx + 16)]        = (_Float16)a01;
        W1[(f0 + fy + 16) * F_DIM + (j0 + jx)]        = (_Float16)a10;
        W1[(f0 + fy + 16) * F_DIM + (j0 + jx + 16)]   = (_Float16)a11;
    } else {
        const long co = (mode == 2) ? F_DIM : 0;
        W2[(long)(f0 + fy) * 1024 + co + (j0 + jx)]           = (_Float16)a00;
        W2[(long)(f0 + fy) * 1024 + co + (j0 + jx + 16)]      = (_Float16)a01;
        W2[(long)(f0 + fy + 16) * 1024 + co + (j0 + jx)]      = (_Float16)a10;
        W2[(long)(f0 + fy + 16) * 1024 + co + (j0 + jx + 16)] = (_Float16)a11;
    }
}

// ---------------------------------------------------------------------------
// Mega-kernel: 16-row stripe per block, 256 threads, grid 1024.
//  phase 0: stage g (f32->f16) into Acat[:,512:1024]
//  phase 1: T = G @ W1^T + c1  (MFMA; B-frags direct from L2-hot W1; no k-barriers)
//  phase 2: local pass: softmax over 12 via t, pooled -> Acat[:,0:512],
//           base = lfm + g -> overlaid into T storage
//  phase 3: out = relu(Acat @ W2^T + cvec) + base  (B-frags direct from W2)
// LDS: Acat 16x1048 f16 (33.5KB) + T 16x520 f16 (16.6KB) = 50.2KB -> 3 blocks/CU.
// Only 3 __syncthreads per block lifetime.
// ---------------------------------------------------------------------------
#define ACS 1048   // Acat LDS stride (halfs); 2096B: 16B-aligned rows, ~2-way banking
#define TS  520    // T LDS stride (halfs)

__global__ void __launch_bounds__(256) mega(
    const float* __restrict__ g, const float* __restrict__ loc,
    const _Float16* __restrict__ W1, const _Float16* __restrict__ W2,
    const float* __restrict__ c1, const float* __restrict__ cvec,
    const float* __restrict__ wdr, const float* __restrict__ bdr,
    float* __restrict__ out)
{
    __shared__ _Float16 Acat[16 * ACS];
    __shared__ _Float16 T[16 * TS];
    const int tid = threadIdx.x;
    const int lane = tid & 63;
    const int wave = tid >> 6;
    const int quad = lane >> 4;
    const int l16 = lane & 15;
    const long m0 = (long)blockIdx.x * 16;

    // ---- phase 0: stage g rows (fully coalesced f4 loads)
#pragma unroll
    for (int it = 0; it < 8; ++it) {
        const int idx = it * 1024 + tid * 4;      // flat over 16x512
        const int row = idx >> 9;
        const int col = idx & 511;
        f4 v = *(const f4*)(g + (m0 + row) * F_DIM + col);
        half4 hv;
#pragma unroll
        for (int j = 0; j < 4; ++j) hv[j] = (_Float16)v[j];
        *(half4*)&Acat[row * ACS + 512 + col] = hv;
    }
    __syncthreads();

    // ---- phase 1: T = G @ W1^T + c1 ; wave owns 128 output cols, no barriers
    {
        const int wn = wave * 128;
        f4 acc[8];
#pragma unroll
        for (int nj = 0; nj < 8; ++nj) acc[nj] = (f4){0.f, 0.f, 0.f, 0.f};
        for (int k0 = 0; k0 < 512; k0 += 32) {
            half8 a0 = *(const half8*)&Acat[l16 * ACS + 512 + k0 + quad * 8];
#pragma unroll
            for (int nj = 0; nj < 8; ++nj) {
                half8 b = *(const half8*)(W1 + (long)(wn + nj * 16 + l16) * 512 + k0 + quad * 8);
                acc[nj] = __builtin_amdgcn_mfma_f32_16x16x32_f16(a0, b, acc[nj], 0, 0, 0);
            }
        }
#pragma unroll
        for (int nj = 0; nj < 8; ++nj) {
            const int col = wn + nj * 16 + l16;
            const float cv = c1[col];
#pragma unroll
            for (int i = 0; i < 4; ++i)
                T[(quad * 4 + i) * TS + col] = (_Float16)(acc[nj][i] + cv);
        }
    }
    __syncthreads();

    // ---- phase 2: local pass; 4 rows per wave; t/g from LDS
    {
        const int c0 = lane * 4;
        const int c1i = 256 + lane * 4;
        const float bd = bdr[0];
        float wv[NLOC];
#pragma unroll
        for (int k = 0; k < NLOC; ++k) wv[k] = wdr[k];

#pragma unroll
        for (int rr = 0; rr < 4; ++rr) {
            const int bl = wave * 4 + rr;
            const long b = m0 + bl;
            const float* lb = loc + b * (NLOC * F_DIM);

            f4 la[NLOC], lbv[NLOC];
#pragma unroll
            for (int k = 0; k < NLOC; ++k) {
                la[k]  = *(const f4*)(lb + k * F_DIM + c0);
                lbv[k] = *(const f4*)(lb + k * F_DIM + c1i);
            }
            f4 taf = __builtin_convertvector(*(const half4*)&T[bl * TS + c0], f4);
            f4 tbf = __builtin_convertvector(*(const half4*)&T[bl * TS + c1i], f4);

            float p[NLOC];
#pragma unroll
            for (int k = 0; k < NLOC; ++k) {
                f4 prod = la[k] * taf + lbv[k] * tbf;
                p[k] = prod[0] + prod[1] + prod[2] + prod[3];
            }
#pragma unroll
            for (int k = 0; k < NLOC; ++k) {
                float v = p[k];
                v += __shfl_xor(v, 1);
                v += __shfl_xor(v, 2);
                v += __shfl_xor(v, 4);
                v += __shfl_xor(v, 8);
                v += __shfl_xor(v, 16);
                v += __shfl_xor(v, 32);
                p[k] = v * 0.0625f;   // scale = 1/sqrt(256)
            }
            float mx = p[0];
#pragma unroll
            for (int k = 1; k < NLOC; ++k) mx = fmaxf(mx, p[k]);
            float e[NLOC], s = 0.f;
#pragma unroll
            for (int k = 0; k < NLOC; ++k) { e[k] = expf(p[k] - mx); s += e[k]; }
            const float inv = 1.f / s;

            f4 pA = {0.f,0.f,0.f,0.f}, pB = {0.f,0.f,0.f,0.f};
            f4 fA = {0.f,0.f,0.f,0.f}, fB = {0.f,0.f,0.f,0.f};
#pragma unroll
            for (int k = 0; k < NLOC; ++k) {
                const float ak = e[k] * inv;
                const float wk = wv[k];
                pA += ak * la[k]; pB += ak * lbv[k];
                fA += wk * la[k]; fB += wk * lbv[k];
            }
            f4 gA = __builtin_convertvector(*(const half4*)&Acat[bl * ACS + 512 + c0], f4);
            f4 gB = __builtin_convertvector(*(const half4*)&Acat[bl * ACS + 512 + c1i], f4);
            fA += bd + gA;
            fB += bd + gB;

            *(half4*)&Acat[bl * ACS + c0]  = __builtin_convertvector(pA, half4);
            *(half4*)&Acat[bl * ACS + c1i] = __builtin_convertvector(pB, half4);
            // overlay base into T storage (same lanes own same elements)
            *(half4*)&T[bl * TS + c0]  = __builtin_convertvector(fA, half4);
            *(half4*)&T[bl * TS + c1i] = __builtin_convertvector(fB, half4);
        }
    }
    __syncthreads();

    // ---- phase 3: out = relu(Acat @ W2^T + cvec) + base ; wave owns 128 cols
    {
        const int wn = wave * 128;
        f4 acc[8];
#pragma unroll
        for (int nj = 0; nj < 8; ++nj) acc[nj] = (f4){0.f, 0.f, 0.f, 0.f};
        for (int k0 = 0; k0 < 1024; k0 += 32) {
            half8 a0 = *(const half8*)&Acat[l16 * ACS + k0 + quad * 8];
#pragma unroll
            for (int nj = 0; nj < 8; ++nj) {
                half8 b = *(const half8*)(W2 + (long)(wn + nj * 16 + l16) * 1024 + k0 + quad * 8);
                acc[nj] = __builtin_amdgcn_mfma_f32_16x16x32_f16(a0, b, acc[nj], 0, 0, 0);
            }
        }
#pragma unroll
        for (int nj = 0; nj < 8; ++nj) {
            const int col = wn + nj * 16 + l16;
            const float cv = cvec[col];
#pragma unroll
            for (int i = 0; i < 4; ++i) {
                const int rl = quad * 4 + i;
                float v = fmaxf(acc[nj][i] + cv, 0.f) + (float)T[rl * TS + col];
                out[(m0 + rl) * F_DIM + col] = v;
            }
        }
    }
}

// ---------------------------------------------------------------------------
extern "C" void kernel_launch(void* const* d_in, const int* in_sizes, int n_in,
                              void* d_out, int out_size, void* d_ws, size_t ws_size,
                              hipStream_t stream)
{
    (void)in_sizes; (void)n_in; (void)out_size; (void)ws_size;
    const float* gf  = (const float*)d_in[0];
    const float* loc = (const float*)d_in[1];
    const float* Wq  = (const float*)d_in[2];
    const float* bq  = (const float*)d_in[3];
    const float* Wk  = (const float*)d_in[4];
    // d_in[5] = bk: dropped — contributes only a k-constant to s2 (softmax-invariant)
    const float* Wv  = (const float*)d_in[6];
    const float* bv  = (const float*)d_in[7];
    const float* wdr = (const float*)d_in[8];
    const float* bdr = (const float*)d_in[9];
    const float* Wf  = (const float*)d_in[10];
    const float* bfv = (const float*)d_in[11];
    float* out = (float*)d_out;

    char* ws = (char*)d_ws;
    _Float16* W1   = (_Float16*)(ws + OFF_W1);
    _Float16* W2   = (_Float16*)(ws + OFF_W2);
    float*    c1   = (float*)(ws + OFF_C1);
    float*    cvec = (float*)(ws + OFF_CVEC);

    precompute_w<<<dim3(16, 16, 4), 256, 0, stream>>>(Wq, Wk, Wv, Wf, bq, bv,
                                                      wdr, bdr, bfv, W1, W2, c1, cvec);
    mega<<<1024, 256, 0, stream>>>(gf, loc, W1, W2, c1, cvec, wdr, bdr, out);
}